// Round 10
// baseline (234.597 us; speedup 1.0000x reference)
//
#include <hip/hip_runtime.h>
#include <hip/hip_bf16.h>
#include <math.h>

#define B_ 16
#define C_ 64
#define H_ 64
#define W_ 64
#define KSTEPS 18

typedef __attribute__((ext_vector_type(8))) short bf16x8;
typedef __attribute__((ext_vector_type(4))) short bf16x4;
typedef __attribute__((ext_vector_type(4))) float f32x4;

static __device__ __forceinline__ unsigned short f2b(float f) {
    __hip_bfloat16 h = __float2bfloat16(f);
    return *reinterpret_cast<unsigned short*>(&h);
}
static __device__ __forceinline__ float b2f(unsigned short u) {
    __hip_bfloat16 h;
    *reinterpret_cast<unsigned short*>(&h) = u;
    return __bfloat162float(h);
}

// ---------------------------------------------------------------------------
// prep: pack Wp (bf16, A-frag order) + bnp (f32 [plane][{inv,bias}][64]).
// mf 0-3 q (center tap), 4-7 k (3x3), 8-11 v (center tap). k idx = tap*64+c.
// ---------------------------------------------------------------------------
__global__ __launch_bounds__(64) void prep_kernel(
    const float* __restrict__ wq, const float* __restrict__ wk, const float* __restrict__ wv,
    const float* __restrict__ qg, const float* __restrict__ qb, const float* __restrict__ qm, const float* __restrict__ qv,
    const float* __restrict__ kg, const float* __restrict__ kb, const float* __restrict__ km, const float* __restrict__ kv,
    const float* __restrict__ vg, const float* __restrict__ vb, const float* __restrict__ vm, const float* __restrict__ vv,
    const float* __restrict__ og, const float* __restrict__ ob, const float* __restrict__ om, const float* __restrict__ ov,
    unsigned short* __restrict__ Wp, float* __restrict__ bnp)
{
    const int bid = blockIdx.x;
    const int lane = threadIdx.x;
    if (bid < 12 * KSTEPS) {
        const int mf = bid / KSTEPS;
        const int ks = bid % KSTEPS;
        const int r = lane & 15;
        bf16x8 u;
#pragma unroll
        for (int j = 0; j < 8; j++) {
            int k = ks * 32 + ((lane >> 4) << 3) + j;
            int tap = k >> 6;
            int c = k & 63;
            float w;
            if (mf < 4)      { int co = mf * 16 + r;        w = (tap == 4) ? wq[co * 64 + c] : 0.f; }
            else if (mf < 8) { int co = (mf - 4) * 16 + r;  w = wk[(co * 64 + c) * 9 + tap]; }
            else             { int co = (mf - 8) * 16 + r;  w = (tap == 4) ? wv[co * 64 + c] : 0.f; }
            u[j] = (short)f2b(w);
        }
        *reinterpret_cast<bf16x8*>(Wp + ((size_t)(mf * KSTEPS + ks) * 64 + lane) * 8) = u;
    } else {
        const int c = lane;
        const float* G[4] = {qg, kg, vg, og};
        const float* Bt[4] = {qb, kb, vb, ob};
        const float* M[4] = {qm, km, vm, om};
        const float* V[4] = {qv, kv, vv, ov};
#pragma unroll
        for (int p = 0; p < 4; p++) {
            float inv = G[p][c] * rsqrtf(V[p][c] + 1e-5f);
            bnp[p * 128 + c] = inv;
            bnp[p * 128 + 64 + c] = Bt[p][c] - M[p][c] * inv;
        }
    }
}

// ---------------------------------------------------------------------------
// xt: transpose x NCHW f32 -> xt[(b,h,w),c] bf16 (channel-fastest).
// ---------------------------------------------------------------------------
__global__ __launch_bounds__(256) void xt_kernel(
    const float* __restrict__ x, unsigned short* __restrict__ xt)
{
    __shared__ float ls[64][65];
    const int b = blockIdx.x >> 6;
    const int h = blockIdx.x & 63;
    const int tid = threadIdx.x;
    const int w = tid & 63;
    const int cg = tid >> 6;          // 0..3
#pragma unroll
    for (int cc = 0; cc < 16; cc++) {
        int c = cg * 16 + cc;
        ls[c][w] = x[((b * 64 + c) * 64 + h) * 64 + w];
    }
    __syncthreads();
    const int px = tid & 63;
    bf16x8 u0, u1;
#pragma unroll
    for (int j = 0; j < 8; j++) {
        u0[j] = (short)f2b(ls[cg * 16 + j][px]);
        u1[j] = (short)f2b(ls[cg * 16 + 8 + j][px]);
    }
    size_t base = ((size_t)((b * 64 + h) * 64 + px)) * 64 + cg * 16;
    *reinterpret_cast<bf16x8*>(xt + base) = u0;
    *reinterpret_cast<bf16x8*>(xt + base + 8) = u1;
}

// ---------------------------------------------------------------------------
// fused v3: per (b, output row h).  512 threads = 8 waves.
// LDS layouts are c-chunk-major (16B unit = 8 channels), so EVERY LDS access
// is (per-lane base + compile-time immediate) and stride-16B across lanes:
//   xs  [8 ch-chunks][5 rows][66 cols]  chunk stride 5280 B, row 1056 B
//   ksm/vsm [8][3 rows][66 cols]        chunk stride 3168 B  (+VSM_OFF for v)
//   qsm [8][64 px]                      chunk stride 1024 B
// Split GEMM: k-conv M=64/K=576; q/v (1x1) piggyback on tap-4 steps (ks 8,9).
// No XOR swizzle anywhere; all patterns bank-conflict-free by construction.
// ---------------------------------------------------------------------------
#define KSM_OFF 0
#define VSM_OFF 25344
#define QSM_OFF 50688
__global__ __launch_bounds__(512, 4) void fused_kernel(
    const unsigned short* __restrict__ xt, const unsigned short* __restrict__ Wp,
    const float* __restrict__ bnp,
    const float* __restrict__ ph, const float* __restrict__ pw,
    float* __restrict__ out)
{
    __shared__ __align__(16) char smem[58880];   // xs (42240); then ksm/vsm/qsm
    __shared__ float bns[512];
    __shared__ float phs[192], pws[192];
    const int bid = blockIdx.x;
    const int b = bid >> 6;
    const int h = bid & 63;
    const int tid = threadIdx.x;

    // ---- phase 0: stage x rows h-2..h+2, cols -1..64 (zero OOB) ----
    for (int i = tid; i < 8 * 5 * 66; i += 512) {
        int ch   = i & 7;                 // chunk (8 channels)
        int rest = i >> 3;                // 0..329
        int col  = rest % 66;
        int dy   = rest / 66;
        int gh = h - 2 + dy, gw = col - 1;
        bf16x8 u = (bf16x8){0,0,0,0,0,0,0,0};
        if ((unsigned)gh < 64u && (unsigned)gw < 64u)
            u = *reinterpret_cast<const bf16x8*>(xt + ((size_t)((b * 64 + gh) * 64 + gw)) * 64 + ch * 8);
        *reinterpret_cast<bf16x8*>(smem + ch * 5280 + dy * 1056 + col * 16) = u;
    }
    bns[tid & 511] = bnp[tid & 511];
    if (tid < 192) { phs[tid] = ph[tid]; pws[tid] = pw[tid]; }
    __syncthreads();

    // ---- phase 1: GEMM ----
    const int wid = tid >> 6, lane = tid & 63;
    const int mf = wid & 3, half = wid >> 2;
    const int t = lane & 15, q4 = lane >> 4;
    const int qbase = half ? 0 : 4;          // local n of q-frags (row 1)
    const int vb16 = q4 * 5280 + t * 16;     // per-lane xs base

    const unsigned short* WpQ = Wp + (size_t)(mf * KSTEPS) * 512 + lane * 8;
    const unsigned short* WpK = Wp + (size_t)((4 + mf) * KSTEPS) * 512 + lane * 8;
    const unsigned short* WpV = Wp + (size_t)((8 + mf) * KSTEPS) * 512 + lane * 8;

    f32x4 acck[6], accv[6], accq[2];
#pragma unroll
    for (int n = 0; n < 6; n++) { acck[n] = (f32x4){0.f,0.f,0.f,0.f}; accv[n] = (f32x4){0.f,0.f,0.f,0.f}; }
    accq[0] = (f32x4){0.f,0.f,0.f,0.f}; accq[1] = (f32x4){0.f,0.f,0.f,0.f};

#pragma unroll
    for (int ks = 0; ks < KSTEPS; ks++) {
        const int tap = ks >> 1;
        const int dy = tap / 3, dx = tap - dy * 3;       // compile-time
        const int koff = (ks & 1) * 21120;               // (ks&1)*4 chunks
        bf16x8 bf[6];
#pragma unroll
        for (int n = 0; n < 6; n++) {
            const int n16 = (half * 6 + n) * 16;         // compile-time
            const int r = n16 >> 6;                      // tile row of frag
            const int colw0 = n16 & 63;                  // col base of frag
            bf[n] = *reinterpret_cast<const bf16x8*>(
                smem + vb16 + koff + (r + dy) * 1056 + (colw0 + dx) * 16);
        }
        bf16x8 afk = *reinterpret_cast<const bf16x8*>(WpK + (size_t)ks * 512);
#pragma unroll
        for (int n = 0; n < 6; n++)
            acck[n] = __builtin_amdgcn_mfma_f32_16x16x32_bf16(afk, bf[n], acck[n], 0, 0, 0);
        if (ks == 8 || ks == 9) {                        // tap 4: q,v live
            bf16x8 afq = *reinterpret_cast<const bf16x8*>(WpQ + (size_t)ks * 512);
            bf16x8 afv = *reinterpret_cast<const bf16x8*>(WpV + (size_t)ks * 512);
#pragma unroll
            for (int n = 0; n < 6; n++)
                accv[n] = __builtin_amdgcn_mfma_f32_16x16x32_bf16(afv, bf[n], accv[n], 0, 0, 0);
            accq[0] = __builtin_amdgcn_mfma_f32_16x16x32_bf16(afq, bf[qbase], accq[0], 0, 0, 0);
            accq[1] = __builtin_amdgcn_mfma_f32_16x16x32_bf16(afq, bf[qbase + 1], accq[1], 0, 0, 0);
        }
    }
    __syncthreads();   // xs fully consumed; region reused for k/v/q

    // ---- phase 2: BN epilogue into LDS (c-chunk-major) ----
    const int c0 = mf * 16 + q4 * 4;
    const int ech = c0 >> 3;                 // chunk
    const int esub = (q4 & 1) * 8;           // byte offset within chunk
    {
        f32x4 invk  = *reinterpret_cast<const f32x4*>(&bns[128 + c0]);
        f32x4 biask = *reinterpret_cast<const f32x4*>(&bns[128 + 64 + c0]);
        f32x4 invv  = *reinterpret_cast<const f32x4*>(&bns[256 + c0]);
        f32x4 biasv = *reinterpret_cast<const f32x4*>(&bns[256 + 64 + c0]);
        const int ebase = ech * 3168 + esub + t * 16;
#pragma unroll
        for (int n = 0; n < 6; n++) {
            const int n16 = (half * 6 + n) * 16;
            const int r = n16 >> 6;
            const int colw0 = n16 & 63;
            bf16x4 pk, pv;
#pragma unroll
            for (int j = 0; j < 4; j++) {
                pk[j] = (short)f2b(fmaxf(acck[n][j] * invk[j] + biask[j], 0.f));
                pv[j] = (short)f2b(accv[n][j] * invv[j] + biasv[j]);
            }
            const int off = r * 1056 + (colw0 + 1) * 16;   // pxp = colw+1
            *reinterpret_cast<bf16x4*>(smem + KSM_OFF + ebase + off) = pk;
            *reinterpret_cast<bf16x4*>(smem + VSM_OFF + ebase + off) = pv;
        }
        f32x4 invq  = *reinterpret_cast<const f32x4*>(&bns[c0]);
        f32x4 biasq = *reinterpret_cast<const f32x4*>(&bns[64 + c0]);
        const int qb16 = QSM_OFF + ech * 1024 + esub + t * 16;
#pragma unroll
        for (int i = 0; i < 2; i++) {
            const int nq = 4 + half * 2 + i;               // global nf (row 1)
            bf16x4 pq;
#pragma unroll
            for (int j = 0; j < 4; j++)
                pq[j] = (short)f2b(fmaxf(accq[i][j] * invq[j] + biasq[j], 0.f));
            *reinterpret_cast<bf16x4*>(smem + qb16 + (nq & 3) * 256) = pq;
        }
    }
    __syncthreads();

    // ---- zero halo cols (pxp 0,65) and OOB rows of ksm/vsm ----
    const bf16x8 z8 = (bf16x8){0,0,0,0,0,0,0,0};
    for (int i = tid; i < 96; i += 512) {
        int buf = i & 1;
        int j = i >> 1;
        int ch = j & 7;
        int jj = j >> 3;             // 0..5
        int col = (jj & 1) ? 65 : 0;
        int rr = jj >> 1;
        *reinterpret_cast<bf16x8*>(smem + (buf ? VSM_OFF : KSM_OFF)
                                   + ch * 3168 + rr * 1056 + col * 16) = z8;
    }
    int rbad = (h == 0) ? 0 : ((h == 63) ? 2 : -1);
    if (rbad >= 0) {
        for (int i = tid; i < 66 * 8 * 2; i += 512) {
            int buf = i & 1;
            int j = i >> 1;
            int ch = j & 7;
            int col = j >> 3;        // 0..65
            *reinterpret_cast<bf16x8*>(smem + (buf ? VSM_OFF : KSM_OFF)
                                       + ch * 3168 + rbad * 1056 + col * 16) = z8;
        }
    }
    __syncthreads();

    // ---- phase 3: attention ----
    const int px = tid & 63;
    const int head = tid >> 6;
    const int cb = head * 8;
    const int abase = head * 3168 + px * 16;   // per-lane k/v base

    float qf[8];
    {
        bf16x8 q8 = *reinterpret_cast<const bf16x8*>(smem + QSM_OFF + head * 1024 + px * 16);
#pragma unroll
        for (int j = 0; j < 8; j++) qf[j] = b2f((unsigned short)q8[j]);
    }

    float A[3], Bx[3];
#pragma unroll
    for (int tt = 0; tt < 3; tt++) {
        float a = 0.f, bb = 0.f;
#pragma unroll
        for (int j = 0; j < 8; j++) {
            a  = fmaf(qf[j], phs[(cb + j) * 3 + tt], a);
            bb = fmaf(qf[j], pws[(cb + j) * 3 + tt], bb);
        }
        A[tt] = a; Bx[tt] = bb;
    }

    float logit[9];
#pragma unroll
    for (int dy = 0; dy < 3; dy++) {
#pragma unroll
        for (int dx = 0; dx < 3; dx++) {
            bf16x8 k8 = *reinterpret_cast<const bf16x8*>(
                smem + KSM_OFF + abase + dy * 1056 + dx * 16);
            float qk = 0.f;
#pragma unroll
            for (int j = 0; j < 8; j++) qk = fmaf(qf[j], b2f((unsigned short)k8[j]), qk);
            logit[dy * 3 + dx] = qk + A[dy] + Bx[dx];
        }
    }

    float mx = logit[0];
#pragma unroll
    for (int tt = 1; tt < 9; tt++) mx = fmaxf(mx, logit[tt]);
    float e[9], sum = 0.f;
#pragma unroll
    for (int tt = 0; tt < 9; tt++) { e[tt] = __expf(logit[tt] - mx); sum += e[tt]; }
    float inv = 1.f / sum;

    float o[8];
#pragma unroll
    for (int j = 0; j < 8; j++) o[j] = 0.f;
#pragma unroll
    for (int dy = 0; dy < 3; dy++) {
#pragma unroll
        for (int dx = 0; dx < 3; dx++) {
            bf16x8 v8 = *reinterpret_cast<const bf16x8*>(
                smem + VSM_OFF + abase + dy * 1056 + dx * 16);
            float w = e[dy * 3 + dx];
#pragma unroll
            for (int j = 0; j < 8; j++) o[j] = fmaf(w, b2f((unsigned short)v8[j]), o[j]);
        }
    }

#pragma unroll
    for (int j = 0; j < 8; j++) {
        int c = cb + j;
        float val = fmaxf(fmaf(o[j] * inv, bns[384 + c], bns[384 + 64 + c]), 0.f);
        out[((size_t)(b * C_ + c) * H_ + h) * W_ + px] = val;
    }
}

// ---------------------------------------------------------------------------
extern "C" void kernel_launch(void* const* d_in, const int* in_sizes, int n_in,
                              void* d_out, int out_size, void* d_ws, size_t ws_size,
                              hipStream_t stream)
{
    const float* x   = (const float*)d_in[0];
    const float* wq  = (const float*)d_in[1];
    const float* wk  = (const float*)d_in[2];
    const float* wv  = (const float*)d_in[3];
    const float* ph  = (const float*)d_in[4];
    const float* pw  = (const float*)d_in[5];
    const float* qg  = (const float*)d_in[6];
    const float* qb  = (const float*)d_in[7];
    const float* qm  = (const float*)d_in[8];
    const float* qv  = (const float*)d_in[9];
    const float* kg  = (const float*)d_in[10];
    const float* kb  = (const float*)d_in[11];
    const float* km  = (const float*)d_in[12];
    const float* kv  = (const float*)d_in[13];
    const float* vg  = (const float*)d_in[14];
    const float* vb  = (const float*)d_in[15];
    const float* vm  = (const float*)d_in[16];
    const float* vv  = (const float*)d_in[17];
    const float* og  = (const float*)d_in[18];
    const float* ob  = (const float*)d_in[19];
    const float* om  = (const float*)d_in[20];
    const float* ov  = (const float*)d_in[21];

    char* ws = (char*)d_ws;
    unsigned short* Wp = (unsigned short*)ws;                 // 221184 B
    float* bnp = (float*)(ws + 221184);                       // 2048 B
    unsigned short* xt = (unsigned short*)(ws + 223232);      // 8.39 MB

    prep_kernel<<<12 * KSTEPS + 1, 64, 0, stream>>>(
        wq, wk, wv, qg, qb, qm, qv, kg, kb, km, kv, vg, vb, vm, vv,
        og, ob, om, ov, Wp, bnp);

    xt_kernel<<<B_ * H_, 256, 0, stream>>>(x, xt);

    fused_kernel<<<B_ * H_, 512, 0, stream>>>(xt, Wp, bnp, ph, pw, (float*)d_out);
}

// Round 12
// 151.766 us; speedup vs baseline: 1.5458x; 1.5458x over previous
//
#include <hip/hip_runtime.h>
#include <hip/hip_bf16.h>
#include <math.h>

#define B_ 16
#define C_ 64
#define H_ 64
#define W_ 64
#define KSTEPS 18

typedef __attribute__((ext_vector_type(8))) short bf16x8;
typedef __attribute__((ext_vector_type(4))) short bf16x4;
typedef __attribute__((ext_vector_type(4))) float f32x4;

static __device__ __forceinline__ unsigned short f2b(float f) {
    __hip_bfloat16 h = __float2bfloat16(f);
    return *reinterpret_cast<unsigned short*>(&h);
}
static __device__ __forceinline__ float b2f(unsigned short u) {
    __hip_bfloat16 h;
    *reinterpret_cast<unsigned short*>(&h) = u;
    return __bfloat162float(h);
}

// ---------------------------------------------------------------------------
// prep: pack Wp (bf16, A-frag order) + bnp (f32 [plane][{inv,bias}][64]).
// mf 0-3 q (center tap), 4-7 k (3x3), 8-11 v (center tap). k idx = tap*64+c.
// ---------------------------------------------------------------------------
__global__ __launch_bounds__(64) void prep_kernel(
    const float* __restrict__ wq, const float* __restrict__ wk, const float* __restrict__ wv,
    const float* __restrict__ qg, const float* __restrict__ qb, const float* __restrict__ qm, const float* __restrict__ qv,
    const float* __restrict__ kg, const float* __restrict__ kb, const float* __restrict__ km, const float* __restrict__ kv,
    const float* __restrict__ vg, const float* __restrict__ vb, const float* __restrict__ vm, const float* __restrict__ vv,
    const float* __restrict__ og, const float* __restrict__ ob, const float* __restrict__ om, const float* __restrict__ ov,
    unsigned short* __restrict__ Wp, float* __restrict__ bnp)
{
    const int bid = blockIdx.x;
    const int lane = threadIdx.x;
    if (bid < 12 * KSTEPS) {
        const int mf = bid / KSTEPS;
        const int ks = bid % KSTEPS;
        const int r = lane & 15;
        bf16x8 u;
#pragma unroll
        for (int j = 0; j < 8; j++) {
            int k = ks * 32 + ((lane >> 4) << 3) + j;
            int tap = k >> 6;
            int c = k & 63;
            float w;
            if (mf < 4)      { int co = mf * 16 + r;        w = (tap == 4) ? wq[co * 64 + c] : 0.f; }
            else if (mf < 8) { int co = (mf - 4) * 16 + r;  w = wk[(co * 64 + c) * 9 + tap]; }
            else             { int co = (mf - 8) * 16 + r;  w = (tap == 4) ? wv[co * 64 + c] : 0.f; }
            u[j] = (short)f2b(w);
        }
        *reinterpret_cast<bf16x8*>(Wp + ((size_t)(mf * KSTEPS + ks) * 64 + lane) * 8) = u;
    } else {
        const int c = lane;
        const float* G[4] = {qg, kg, vg, og};
        const float* Bt[4] = {qb, kb, vb, ob};
        const float* M[4] = {qm, km, vm, om};
        const float* V[4] = {qv, kv, vv, ov};
#pragma unroll
        for (int p = 0; p < 4; p++) {
            float inv = G[p][c] * rsqrtf(V[p][c] + 1e-5f);
            bnp[p * 128 + c] = inv;
            bnp[p * 128 + 64 + c] = Bt[p][c] - M[p][c] * inv;
        }
    }
}

// ---------------------------------------------------------------------------
// xt: transpose x NCHW f32 -> xt[(b,h,w),c] bf16 (channel-fastest).
// ---------------------------------------------------------------------------
__global__ __launch_bounds__(256) void xt_kernel(
    const float* __restrict__ x, unsigned short* __restrict__ xt)
{
    __shared__ float ls[64][65];
    const int b = blockIdx.x >> 6;
    const int h = blockIdx.x & 63;
    const int tid = threadIdx.x;
    const int w = tid & 63;
    const int cg = tid >> 6;          // 0..3
#pragma unroll
    for (int cc = 0; cc < 16; cc++) {
        int c = cg * 16 + cc;
        ls[c][w] = x[((b * 64 + c) * 64 + h) * 64 + w];
    }
    __syncthreads();
    const int px = tid & 63;
    bf16x8 u0, u1;
#pragma unroll
    for (int j = 0; j < 8; j++) {
        u0[j] = (short)f2b(ls[cg * 16 + j][px]);
        u1[j] = (short)f2b(ls[cg * 16 + 8 + j][px]);
    }
    size_t base = ((size_t)((b * 64 + h) * 64 + px)) * 64 + cg * 16;
    *reinterpret_cast<bf16x8*>(xt + base) = u0;
    *reinterpret_cast<bf16x8*>(xt + base + 8) = u1;
}

// ---------------------------------------------------------------------------
// fused v5: c-chunk-major imm-offset LDS layout + split GEMM (round 9/10
// semantics).  q-frag selection is a branchless wave-uniform ternary into
// named temporaries (no runtime array index, no control flow).
// LDS maps:
//   xs  [8 ch-chunks][5 rows][66 cols]  chunk stride 5280 B, row 1056 B
//   ksm/vsm [8][3 rows][66 cols]        chunk stride 3168 B
//   qsm [8][64 px]                      chunk stride 1024 B
// ---------------------------------------------------------------------------
#define KSM_OFF 0
#define VSM_OFF 25344
#define QSM_OFF 50688
__global__ __launch_bounds__(512, 2) void fused_kernel(
    const unsigned short* __restrict__ xt, const unsigned short* __restrict__ Wp,
    const float* __restrict__ bnp,
    const float* __restrict__ ph, const float* __restrict__ pw,
    float* __restrict__ out)
{
    __shared__ __align__(16) char smem[58880];   // xs (42240); then ksm/vsm/qsm
    __shared__ float bns[512];
    __shared__ float phs[192], pws[192];
    const int bid = blockIdx.x;
    const int b = bid >> 6;
    const int h = bid & 63;
    const int tid = threadIdx.x;

    // ---- phase 0: stage x rows h-2..h+2, cols -1..64 (zero OOB) ----
    for (int i = tid; i < 8 * 5 * 66; i += 512) {
        int ch   = i & 7;                 // chunk (8 channels)
        int rest = i >> 3;                // 0..329
        int col  = rest % 66;
        int dy   = rest / 66;
        int gh = h - 2 + dy, gw = col - 1;
        bf16x8 u = (bf16x8){0,0,0,0,0,0,0,0};
        if ((unsigned)gh < 64u && (unsigned)gw < 64u)
            u = *reinterpret_cast<const bf16x8*>(xt + ((size_t)((b * 64 + gh) * 64 + gw)) * 64 + ch * 8);
        *reinterpret_cast<bf16x8*>(smem + ch * 5280 + dy * 1056 + col * 16) = u;
    }
    bns[tid & 511] = bnp[tid & 511];
    if (tid < 192) { phs[tid] = ph[tid]; pws[tid] = pw[tid]; }
    __syncthreads();

    // ---- phase 1: GEMM ----
    const int wid = tid >> 6, lane = tid & 63;
    const int mf = wid & 3, half = wid >> 2;
    const int t = lane & 15, q4 = lane >> 4;
    const int vb16 = q4 * 5280 + t * 16;     // per-lane xs base

    const unsigned short* WpQ = Wp + (size_t)(mf * KSTEPS) * 512 + lane * 8;
    const unsigned short* WpK = Wp + (size_t)((4 + mf) * KSTEPS) * 512 + lane * 8;
    const unsigned short* WpV = Wp + (size_t)((8 + mf) * KSTEPS) * 512 + lane * 8;

    f32x4 acck[6], accv[6], accq[2];
#pragma unroll
    for (int n = 0; n < 6; n++) { acck[n] = (f32x4){0.f,0.f,0.f,0.f}; accv[n] = (f32x4){0.f,0.f,0.f,0.f}; }
    accq[0] = (f32x4){0.f,0.f,0.f,0.f}; accq[1] = (f32x4){0.f,0.f,0.f,0.f};

#pragma unroll
    for (int ks = 0; ks < KSTEPS; ks++) {
        const int tap = ks >> 1;
        const int dy = tap / 3, dx = tap - dy * 3;       // compile-time
        const int koff = (ks & 1) * 21120;               // (ks&1)*4 chunks
        bf16x8 bf[6];
#pragma unroll
        for (int n = 0; n < 6; n++) {
            const int n16 = (half * 6 + n) * 16;         // uniform per wave
            const int r = n16 >> 6;                      // tile row of frag
            const int colw0 = n16 & 63;                  // col base of frag
            bf[n] = *reinterpret_cast<const bf16x8*>(
                smem + vb16 + koff + (r + dy) * 1056 + (colw0 + dx) * 16);
        }
        bf16x8 afk = *reinterpret_cast<const bf16x8*>(WpK + (size_t)ks * 512);
#pragma unroll
        for (int n = 0; n < 6; n++)
            acck[n] = __builtin_amdgcn_mfma_f32_16x16x32_bf16(afk, bf[n], acck[n], 0, 0, 0);
        if (ks == 8 || ks == 9) {                        // tap 4: q,v live
            bf16x8 afq = *reinterpret_cast<const bf16x8*>(WpQ + (size_t)ks * 512);
            bf16x8 afv = *reinterpret_cast<const bf16x8*>(WpV + (size_t)ks * 512);
#pragma unroll
            for (int n = 0; n < 6; n++)
                accv[n] = __builtin_amdgcn_mfma_f32_16x16x32_bf16(afv, bf[n], accv[n], 0, 0, 0);
            // q needs row-1 frags: half0 -> bf[4],bf[5] (cols 0..31);
            // half1 -> bf[0],bf[1] (cols 32..63).  Branchless uniform select.
            bf16x8 bq0 = half ? bf[0] : bf[4];
            bf16x8 bq1 = half ? bf[1] : bf[5];
            accq[0] = __builtin_amdgcn_mfma_f32_16x16x32_bf16(afq, bq0, accq[0], 0, 0, 0);
            accq[1] = __builtin_amdgcn_mfma_f32_16x16x32_bf16(afq, bq1, accq[1], 0, 0, 0);
        }
    }
    __syncthreads();   // xs fully consumed; region reused for k/v/q

    // ---- phase 2: BN epilogue into LDS (c-chunk-major) ----
    const int c0 = mf * 16 + q4 * 4;
    const int ech = c0 >> 3;                 // chunk
    const int esub = (q4 & 1) * 8;           // byte offset within chunk
    {
        f32x4 invk  = *reinterpret_cast<const f32x4*>(&bns[128 + c0]);
        f32x4 biask = *reinterpret_cast<const f32x4*>(&bns[128 + 64 + c0]);
        f32x4 invv  = *reinterpret_cast<const f32x4*>(&bns[256 + c0]);
        f32x4 biasv = *reinterpret_cast<const f32x4*>(&bns[256 + 64 + c0]);
        const int ebase = ech * 3168 + esub + t * 16;
#pragma unroll
        for (int n = 0; n < 6; n++) {
            const int n16 = (half * 6 + n) * 16;
            const int r = n16 >> 6;
            const int colw0 = n16 & 63;
            bf16x4 pk, pv;
#pragma unroll
            for (int j = 0; j < 4; j++) {
                pk[j] = (short)f2b(fmaxf(acck[n][j] * invk[j] + biask[j], 0.f));
                pv[j] = (short)f2b(accv[n][j] * invv[j] + biasv[j]);
            }
            const int off = r * 1056 + (colw0 + 1) * 16;   // pxp = colw+1
            *reinterpret_cast<bf16x4*>(smem + KSM_OFF + ebase + off) = pk;
            *reinterpret_cast<bf16x4*>(smem + VSM_OFF + ebase + off) = pv;
        }
        f32x4 invq  = *reinterpret_cast<const f32x4*>(&bns[c0]);
        f32x4 biasq = *reinterpret_cast<const f32x4*>(&bns[64 + c0]);
        const int qb16 = QSM_OFF + ech * 1024 + esub + t * 16;
#pragma unroll
        for (int i = 0; i < 2; i++) {
            const int nq = 4 + half * 2 + i;               // global nf (row 1)
            bf16x4 pq;
#pragma unroll
            for (int j = 0; j < 4; j++)
                pq[j] = (short)f2b(fmaxf(accq[i][j] * invq[j] + biasq[j], 0.f));
            *reinterpret_cast<bf16x4*>(smem + qb16 + (nq & 3) * 256) = pq;
        }
    }
    __syncthreads();

    // ---- zero halo cols (pxp 0,65) and OOB rows of ksm/vsm ----
    const bf16x8 z8 = (bf16x8){0,0,0,0,0,0,0,0};
    for (int i = tid; i < 96; i += 512) {
        int buf = i & 1;
        int j = i >> 1;
        int ch = j & 7;
        int jj = j >> 3;             // 0..5
        int col = (jj & 1) ? 65 : 0;
        int rr = jj >> 1;
        *reinterpret_cast<bf16x8*>(smem + (buf ? VSM_OFF : KSM_OFF)
                                   + ch * 3168 + rr * 1056 + col * 16) = z8;
    }
    int rbad = (h == 0) ? 0 : ((h == 63) ? 2 : -1);
    if (rbad >= 0) {
        for (int i = tid; i < 66 * 8 * 2; i += 512) {
            int buf = i & 1;
            int j = i >> 1;
            int ch = j & 7;
            int col = j >> 3;        // 0..65
            *reinterpret_cast<bf16x8*>(smem + (buf ? VSM_OFF : KSM_OFF)
                                       + ch * 3168 + rbad * 1056 + col * 16) = z8;
        }
    }
    __syncthreads();

    // ---- phase 3: attention ----
    const int px = tid & 63;
    const int head = tid >> 6;
    const int cb = head * 8;
    const int abase = head * 3168 + px * 16;   // per-lane k/v base

    float qf[8];
    {
        bf16x8 q8 = *reinterpret_cast<const bf16x8*>(smem + QSM_OFF + head * 1024 + px * 16);
#pragma unroll
        for (int j = 0; j < 8; j++) qf[j] = b2f((unsigned short)q8[j]);
    }

    float A[3], Bx[3];
#pragma unroll
    for (int tt = 0; tt < 3; tt++) {
        float a = 0.f, bb = 0.f;
#pragma unroll
        for (int j = 0; j < 8; j++) {
            a  = fmaf(qf[j], phs[(cb + j) * 3 + tt], a);
            bb = fmaf(qf[j], pws[(cb + j) * 3 + tt], bb);
        }
        A[tt] = a; Bx[tt] = bb;
    }

    float logit[9];
#pragma unroll
    for (int dy = 0; dy < 3; dy++) {
#pragma unroll
        for (int dx = 0; dx < 3; dx++) {
            bf16x8 k8 = *reinterpret_cast<const bf16x8*>(
                smem + KSM_OFF + abase + dy * 1056 + dx * 16);
            float qk = 0.f;
#pragma unroll
            for (int j = 0; j < 8; j++) qk = fmaf(qf[j], b2f((unsigned short)k8[j]), qk);
            logit[dy * 3 + dx] = qk + A[dy] + Bx[dx];
        }
    }

    float mx = logit[0];
#pragma unroll
    for (int tt = 1; tt < 9; tt++) mx = fmaxf(mx, logit[tt]);
    float e[9], sum = 0.f;
#pragma unroll
    for (int tt = 0; tt < 9; tt++) { e[tt] = __expf(logit[tt] - mx); sum += e[tt]; }
    float inv = 1.f / sum;

    float o[8];
#pragma unroll
    for (int j = 0; j < 8; j++) o[j] = 0.f;
#pragma unroll
    for (int dy = 0; dy < 3; dy++) {
#pragma unroll
        for (int dx = 0; dx < 3; dx++) {
            bf16x8 v8 = *reinterpret_cast<const bf16x8*>(
                smem + VSM_OFF + abase + dy * 1056 + dx * 16);
            float w = e[dy * 3 + dx];
#pragma unroll
            for (int j = 0; j < 8; j++) o[j] = fmaf(w, b2f((unsigned short)v8[j]), o[j]);
        }
    }

#pragma unroll
    for (int j = 0; j < 8; j++) {
        int c = cb + j;
        float val = fmaxf(fmaf(o[j] * inv, bns[384 + c], bns[384 + 64 + c]), 0.f);
        out[((size_t)(b * C_ + c) * H_ + h) * W_ + px] = val;
    }
}

// ---------------------------------------------------------------------------
extern "C" void kernel_launch(void* const* d_in, const int* in_sizes, int n_in,
                              void* d_out, int out_size, void* d_ws, size_t ws_size,
                              hipStream_t stream)
{
    const float* x   = (const float*)d_in[0];
    const float* wq  = (const float*)d_in[1];
    const float* wk  = (const float*)d_in[2];
    const float* wv  = (const float*)d_in[3];
    const float* ph  = (const float*)d_in[4];
    const float* pw  = (const float*)d_in[5];
    const float* qg  = (const float*)d_in[6];
    const float* qb  = (const float*)d_in[7];
    const float* qm  = (const float*)d_in[8];
    const float* qv  = (const float*)d_in[9];
    const float* kg  = (const float*)d_in[10];
    const float* kb  = (const float*)d_in[11];
    const float* km  = (const float*)d_in[12];
    const float* kv  = (const float*)d_in[13];
    const float* vg  = (const float*)d_in[14];
    const float* vb  = (const float*)d_in[15];
    const float* vm  = (const float*)d_in[16];
    const float* vv  = (const float*)d_in[17];
    const float* og  = (const float*)d_in[18];
    const float* ob  = (const float*)d_in[19];
    const float* om  = (const float*)d_in[20];
    const float* ov  = (const float*)d_in[21];

    char* ws = (char*)d_ws;
    unsigned short* Wp = (unsigned short*)ws;                 // 221184 B
    float* bnp = (float*)(ws + 221184);                       // 2048 B
    unsigned short* xt = (unsigned short*)(ws + 223232);      // 8.39 MB

    prep_kernel<<<12 * KSTEPS + 1, 64, 0, stream>>>(
        wq, wk, wv, qg, qb, qm, qv, kg, kb, km, kv, vg, vb, vm, vv,
        og, ob, om, ov, Wp, bnp);

    xt_kernel<<<B_ * H_, 256, 0, stream>>>(x, xt);

    fused_kernel<<<B_ * H_, 512, 0, stream>>>(xt, Wp, bnp, ph, pw, (float*)d_out);
}